// Round 7
// baseline (390.577 us; speedup 1.0000x reference)
//
#include <hip/hip_runtime.h>
#include <math.h>

#define NCAPS 8
#define DD    16
#define D     128
#define M     32
#define ROUTIT 6
#define CUT   5

__device__ __forceinline__ float wred16_sum(float v) {
    v += __shfl_xor(v, 1);
    v += __shfl_xor(v, 2);
    v += __shfl_xor(v, 4);
    v += __shfl_xor(v, 8);
    return v;
}

// ---------------------------------------------------------------- init
__global__ void init_kernel(float* xc0, float* xc1, int n) {
    int t = threadIdx.x;
    if (t < D) {
        xc0[(size_t)n * D + t] = 0.f;   // dummy row n = 0
        xc1[(size_t)n * D + t] = 0.f;
    }
}

// ---------------------------------------------------------------- PCA GEMM
// h[n,128] = x[n,500] @ w[500,128] + bias   (BM=32, BN=128, BK=20, 4x4 microtile)
__global__ __launch_bounds__(256) void pca_gemm(
        const float* __restrict__ x, const float* __restrict__ w,
        const float* __restrict__ bias, float* __restrict__ h,
        int n, int nfeat) {
    __shared__ float xs[20][36];    // [kk][r], pad keeps float4 alignment
    __shared__ float ws[20][128];   // [kk][col]
    const int tid = threadIdx.x;
    const int cg = tid & 31;        // col group: cols cg*4 .. +3
    const int rg = tid >> 5;        // row group: rows rg*4 .. +3
    const int row0 = blockIdx.x * 32;
    float acc[4][4] = {};
    for (int k0 = 0; k0 < nfeat; k0 += 20) {
#pragma unroll
        for (int i = 0; i < 3; ++i) {           // 640 elems of x tile
            int l = tid + i * 256;
            if (l < 640) {
                int r = l / 20, kk = l - r * 20;
                int row = row0 + r;
                xs[kk][r] = (row < n) ? x[(size_t)row * nfeat + k0 + kk] : 0.f;
            }
        }
#pragma unroll
        for (int i = 0; i < 10; ++i) {          // 2560 elems of w tile
            int l = tid + i * 256;
            int kk = l >> 7, col = l & 127;
            ws[kk][col] = w[(size_t)(k0 + kk) * 128 + col];
        }
        __syncthreads();
#pragma unroll
        for (int kk = 0; kk < 20; ++kk) {
            float4 a = *(const float4*)&xs[kk][rg * 4];
            float4 b = *(const float4*)&ws[kk][cg * 4];
            float av[4] = {a.x, a.y, a.z, a.w};
            float bv[4] = {b.x, b.y, b.z, b.w};
#pragma unroll
            for (int i = 0; i < 4; ++i)
#pragma unroll
                for (int j = 0; j < 4; ++j) acc[i][j] += av[i] * bv[j];
        }
        __syncthreads();
    }
#pragma unroll
    for (int i = 0; i < 4; ++i) {
        int row = row0 + rg * 4 + i;
        if (row < n) {
#pragma unroll
            for (int j = 0; j < 4; ++j)
                h[(size_t)row * 128 + cg * 4 + j] = acc[i][j] + bias[cg * 4 + j];
        }
    }
}

// ---------------------------------------------------------------- attn loss + relu-normalize prep
__global__ __launch_bounds__(256) void attn_prep(
        const float* __restrict__ h, const float* __restrict__ ln_g,
        const float* __restrict__ ln_b, const float* __restrict__ w_qs,
        const float* __restrict__ w_ks, float* __restrict__ xc0,
        float* __restrict__ partial, int n) {
    __shared__ float wq[256], wk[256];
    __shared__ float qn[2][8][17], hh[2][8][17], qq[2][8][17], kks[2][8][17];
    __shared__ float red[4];
    const int t = threadIdx.x;
    const int half = t >> 7, tl = t & 127;
    const int k = tl >> 4, c = tl & 15;
    const int v = blockIdx.x * 2 + half;
    wq[t] = w_qs[t];
    wk[t] = w_ks[t];
    float hv = 0.f;
    if (v < n) {
        hv = h[(size_t)v * D + tl];
        float mu = wred16_sum(hv) * (1.f / 16.f);
        float dv = hv - mu;
        float var = wred16_sum(dv * dv) * (1.f / 16.f);
        float rstd = rsqrtf(var + 1e-6f);
        qn[half][k][c] = dv * rstd * ln_g[c] + ln_b[c];
        hh[half][k][c] = hv;
    }
    __syncthreads();
    if (v < n) {
        float q = 0.f, kv = 0.f;
#pragma unroll
        for (int cp = 0; cp < 16; ++cp) {
            q  += qn[half][k][cp] * wq[cp * 16 + c];
            kv += hh[half][k][cp] * wk[cp * 16 + c];
        }
        qq[half][k][c]  = q * 0.25f;   // 1/sqrt(16)
        kks[half][k][c] = kv;
    }
    __syncthreads();
    float offd = 0.f;
    if (v < n && tl < 64) {
        int ki = tl >> 3, j = tl & 7;
        float s = 0.f;
#pragma unroll
        for (int cc = 0; cc < 16; ++cc) s += qq[half][ki][cc] * kks[half][j][cc];
        float mx = s;
        mx = fmaxf(mx, __shfl_xor(mx, 1));
        mx = fmaxf(mx, __shfl_xor(mx, 2));
        mx = fmaxf(mx, __shfl_xor(mx, 4));
        float e = __expf(s - mx);
        float se = e;
        se += __shfl_xor(se, 1);
        se += __shfl_xor(se, 2);
        se += __shfl_xor(se, 4);
        float attn = e / se;
        offd = (j != ki) ? attn : 0.f;
    }
    offd += __shfl_xor(offd, 1);
    offd += __shfl_xor(offd, 2);
    offd += __shfl_xor(offd, 4);
    offd += __shfl_xor(offd, 8);
    offd += __shfl_xor(offd, 16);
    offd += __shfl_xor(offd, 32);
    int lane = t & 63, wid = t >> 6;
    if (lane == 0) red[wid] = offd;
    __syncthreads();
    if (t == 0) partial[blockIdx.x] = red[0] + red[1] + red[2] + red[3];
    if (v < n) {
        float r = fmaxf(hv, 0.f);
        float ss = wred16_sum(r * r);
        xc0[(size_t)v * D + tl] = r / fmaxf(sqrtf(ss), 1e-12f);
    }
}

// ---------------------------------------------------------------- partial-sum reduce
__global__ __launch_bounds__(256) void reduce_kernel(
        const float* __restrict__ partial, float* __restrict__ acc, int npart) {
    __shared__ float red[4];
    const int t = threadIdx.x;
    float s = 0.f;
    for (int i = t; i < npart; i += 256) s += partial[i];
    s += __shfl_xor(s, 1);  s += __shfl_xor(s, 2);
    s += __shfl_xor(s, 4);  s += __shfl_xor(s, 8);
    s += __shfl_xor(s, 16); s += __shfl_xor(s, 32);
    if ((t & 63) == 0) red[t >> 6] = s;
    __syncthreads();
    if (t == 0) acc[0] = red[0] + red[1] + red[2] + red[3];
}

// ---------------------------------------------------------------- routing: ONE WAVE PER NODE
// R6 post-mortem: 4-wave blocks spent ~50% of cycles in barrier convoys
// (3 syncthreads/iter, finalize on 32/256 threads). Single-wave blocks have
// no cross-wave coupling: __syncthreads on a 1-wave group is just the
// lgkmcnt wait. z in LDS with XOR-f4 swizzle (slot = row*32 + (f4 ^ row)):
// every z b128 access is the dense 8-cycle minimum, zero extra conflicts.
// p-step: lane=(m=l&31, khalf=l>>5) -> 4 k's; softmax/argmax via
// shfl_xor(32) + register scan. u-step: lane=(f4=l&31, mhalf=l>>5) ->
// 16 rows; combine via shfl_xor(32); norm via shfl_xor(1,2).
template <bool LAST>
__global__ __launch_bounds__(64) void routing_kernel(
        const float* __restrict__ xc,   // (n+1)*128, normalized, row n = 0
        const int* __restrict__ nb,     // n*32
        float* __restrict__ out,        // LAST ? u1 : xc_next rows [0,n)
        int* __restrict__ amax, int n) {
    __shared__ alignas(16) float zs[M * D];         // 1024 xor-swizzled float4s
    __shared__ alignas(16) float u_s[NCAPS * 20];   // u[k][c] at k*20+c
    __shared__ alignas(16) float pT[NCAPS * 36];    // pT[k][m]
    const int l = threadIdx.x;
    const int v = blockIdx.x;
    const int m  = l & 31;      // p-step: row            (also f4 for u-step)
    const int kh = l >> 5;      // p-step: k in kh*4..+3  (also row-half for u-step)
    const int f4 = m;
    const int mg = kh;

    // ---- stage z (xor-swizzled): lane stages row l>>1, f4s (l&1)*16+i
    {
        int sm = l >> 1, sh = l & 1;
        int src = 0;
        if (l < M) {
            int nbv = nb[(size_t)v * M + l];
            src = (nbv < 0) ? n : nbv;
        }
        int srow = __shfl(src, sm);
        const float4* g = (const float4*)(xc + (size_t)srow * D);
#pragma unroll
        for (int i = 0; i < 16; ++i) {
            int f = sh * 16 + i;
            ((float4*)zs)[sm * 32 + (f ^ sm)] = g[f];
        }
    }
    float4 x3 = ((const float4*)(xc + (size_t)v * D))[f4];
    __syncthreads();   // single wave: compiles to waitcnt only

    // ---- it 0: p uniform = 1/8
    {
        float4 a = make_float4(0.f, 0.f, 0.f, 0.f);
#pragma unroll
        for (int j = 0; j < 16; ++j) {
            int r = mg * 16 + j;
            float4 zf = ((const float4*)zs)[r * 32 + (f4 ^ r)];
            a.x += zf.x; a.y += zf.y; a.z += zf.z; a.w += zf.w;
        }
        a.x += __shfl_xor(a.x, 32); a.y += __shfl_xor(a.y, 32);
        a.z += __shfl_xor(a.z, 32); a.w += __shfl_xor(a.w, 32);
        a.x = a.x * 0.125f + x3.x;  a.y = a.y * 0.125f + x3.y;
        a.z = a.z * 0.125f + x3.z;  a.w = a.w * 0.125f + x3.w;
        float ss = a.x * a.x + a.y * a.y + a.z * a.z + a.w * a.w;
        ss += __shfl_xor(ss, 1); ss += __shfl_xor(ss, 2);
        float inv = 1.f / fmaxf(sqrtf(ss), 1e-12f);
        if (l < 32)
            *(float4*)&u_s[(f4 >> 2) * 20 + (f4 & 3) * 4] =
                make_float4(a.x * inv, a.y * inv, a.z * inv, a.w * inv);
    }
    __syncthreads();

    for (int it = 1; it < ROUTIT; ++it) {
        // ---- p-step: lane (m, kh) computes p for k = kh*4+j
        float pr[4];
#pragma unroll
        for (int j = 0; j < 4; ++j) {
            float s = 0.f;
#pragma unroll
            for (int c4 = 0; c4 < 4; ++c4) {
                int f = kh * 16 + j * 4 + c4;
                float4 zf = ((const float4*)zs)[m * 32 + (f ^ m)];
                float4 uf = *(const float4*)&u_s[(kh * 4 + j) * 20 + c4 * 4];
                s += zf.x * uf.x + zf.y * uf.y + zf.z * uf.z + zf.w * uf.w;
            }
            pr[j] = s;
        }
        float po[4];
#pragma unroll
        for (int j = 0; j < 4; ++j) po[j] = __shfl_xor(pr[j], 32);
        if (LAST && it == ROUTIT - 1) {
            // argmax over all 8 raw p (softmax monotone; first-index tiebreak)
            float p8[8];
#pragma unroll
            for (int j = 0; j < 4; ++j) {
                p8[kh * 4 + j] = pr[j];
                p8[(kh ^ 1) * 4 + j] = po[j];
            }
            float bv = p8[0]; int bi = 0;
#pragma unroll
            for (int k2 = 1; k2 < 8; ++k2)
                if (p8[k2] > bv) { bv = p8[k2]; bi = k2; }
            if (l < 32) amax[(size_t)v * M + m] = bi;
        }
        // |p| <= 1 -> max-free softmax
        float er[4], S = 0.f;
#pragma unroll
        for (int j = 0; j < 4; ++j) { er[j] = __expf(pr[j]); S += er[j]; }
#pragma unroll
        for (int j = 0; j < 4; ++j) S += __expf(po[j]);
        float rS = 1.f / S;
#pragma unroll
        for (int j = 0; j < 4; ++j)
            pT[(kh * 4 + j) * 36 + m] = er[j] * rS;
        __syncthreads();

        // ---- u-step: lane (f4, mg) sums 16 rows
        float pk[16];
        {
            const int k2 = f4 >> 2;
#pragma unroll
            for (int j4 = 0; j4 < 4; ++j4) {
                float4 pp = *(const float4*)&pT[k2 * 36 + mg * 16 + j4 * 4];
                pk[j4 * 4 + 0] = pp.x; pk[j4 * 4 + 1] = pp.y;
                pk[j4 * 4 + 2] = pp.z; pk[j4 * 4 + 3] = pp.w;
            }
        }
        float4 a = make_float4(0.f, 0.f, 0.f, 0.f);
#pragma unroll
        for (int j = 0; j < 16; ++j) {
            int r = mg * 16 + j;
            float4 zf = ((const float4*)zs)[r * 32 + (f4 ^ r)];
            a.x += zf.x * pk[j]; a.y += zf.y * pk[j];
            a.z += zf.z * pk[j]; a.w += zf.w * pk[j];
        }
        a.x += __shfl_xor(a.x, 32); a.y += __shfl_xor(a.y, 32);
        a.z += __shfl_xor(a.z, 32); a.w += __shfl_xor(a.w, 32);
        a.x += x3.x; a.y += x3.y; a.z += x3.z; a.w += x3.w;

        if (it < ROUTIT - 1) {
            float ss = a.x * a.x + a.y * a.y + a.z * a.z + a.w * a.w;
            ss += __shfl_xor(ss, 1); ss += __shfl_xor(ss, 2);
            float inv = 1.f / fmaxf(sqrtf(ss), 1e-12f);
            if (l < 32)
                *(float4*)&u_s[(f4 >> 2) * 20 + (f4 & 3) * 4] =
                    make_float4(a.x * inv, a.y * inv, a.z * inv, a.w * inv);
            __syncthreads();
        } else if (LAST) {
            if (l < 32) ((float4*)(out + (size_t)v * D))[f4] = a;
        } else {
            float r0 = fmaxf(a.x, 0.f), r1 = fmaxf(a.y, 0.f);
            float r2 = fmaxf(a.z, 0.f), r3 = fmaxf(a.w, 0.f);
            float ss = r0 * r0 + r1 * r1 + r2 * r2 + r3 * r3;
            ss += __shfl_xor(ss, 1); ss += __shfl_xor(ss, 2);
            float inv = 1.f / fmaxf(sqrtf(ss), 1e-12f);
            if (l < 32)
                ((float4*)(out + (size_t)v * D))[f4] =
                    make_float4(r0 * inv, r1 * inv, r2 * inv, r3 * inv);
        }
    }
}

// ---------------------------------------------------------------- meta gather + MLP + log_softmax
__global__ __launch_bounds__(256) void meta_kernel(
        const float* __restrict__ u1, const float* __restrict__ xc1,
        const int* __restrict__ nb, const int* __restrict__ amax,
        const float* __restrict__ mlp_w, const float* __restrict__ mlp_b,
        const float* __restrict__ attn_acc, float* __restrict__ d_out, int n) {
    __shared__ float Wl[128 * 16];
    __shared__ float accs[16][132];
    const int t = threadIdx.x;
#pragma unroll
    for (int i = 0; i < 8; ++i) Wl[t + i * 256] = mlp_w[t + i * 256];
    const int g = t >> 4, c = t & 15;
    const int v = blockIdx.x * 16 + g;
    if (blockIdx.x == 0 && t == 0)
        d_out[(size_t)n * 16] = attn_acc[0] * (1.f / (56.f * (float)n));
    if (v < n) {
#pragma unroll
        for (int i = 0; i < 8; ++i) accs[g][i * 16 + c] = 0.f;
        for (int a = 0; a < CUT; ++a) {
            int w = nb[(size_t)v * M + a];
            if (w < 0) continue;
            int i = amax[(size_t)v * M + a];   // first-hop capsule
            float s = 0.f;
#pragma unroll
            for (int b = 0; b < CUT; ++b) {
                int idx = nb[(size_t)w * M + b];
                int jj  = amax[(size_t)w * M + b];
                int im  = (idx < 0) ? n : idx;   // row n = zeros
                s += xc1[(size_t)im * D + jj * DD + c];
            }
            accs[g][i * 16 + c] += s;
        }
#pragma unroll
        for (int i = 0; i < 8; ++i) {
            float meta = u1[(size_t)v * D + i * 16 + c] + accs[g][i * 16 + c] * (1.f / 25.f);
            accs[g][i * 16 + c] = fmaxf(meta, 0.f);   // relu, staged for MLP
        }
    }
    __syncthreads();
    if (v < n) {
        float o = mlp_b[c];
#pragma unroll
        for (int dd = 0; dd < 128; ++dd) o += accs[g][dd] * Wl[dd * 16 + c];
        float mx = o;
        mx = fmaxf(mx, __shfl_xor(mx, 1));
        mx = fmaxf(mx, __shfl_xor(mx, 2));
        mx = fmaxf(mx, __shfl_xor(mx, 4));
        mx = fmaxf(mx, __shfl_xor(mx, 8));
        float e = __expf(o - mx);
        float se = wred16_sum(e);
        float ls = (o - mx) - logf(se);
        d_out[(size_t)v * 16 + c] = ls;
        d_out[(size_t)n * 16 + 1 + (size_t)v * 16 + c] = o;
    }
}

// ---------------------------------------------------------------- launch
extern "C" void kernel_launch(void* const* d_in, const int* in_sizes, int n_in,
                              void* d_out, int out_size, void* d_ws, size_t ws_size,
                              hipStream_t stream) {
    const float* x     = (const float*)d_in[0];
    const int*   nb    = (const int*)d_in[1];
    const float* pca_w = (const float*)d_in[2];
    const float* pca_b = (const float*)d_in[3];
    const float* ln_g  = (const float*)d_in[4];
    const float* ln_b  = (const float*)d_in[5];
    const float* w_qs  = (const float*)d_in[6];
    const float* w_ks  = (const float*)d_in[7];
    const float* mlp_w = (const float*)d_in[8];
    const float* mlp_b = (const float*)d_in[9];
    float* out = (float*)d_out;

    const int d = 128;
    const int nfeat = in_sizes[2] / d;      // 500
    const int n = in_sizes[0] / nfeat;      // 20000
    const int npart = (n + 1) / 2;          // attn_prep block count

    float* bufA = (float*)d_ws;                       // n*128   : h, later u1
    float* bufB = bufA + (size_t)n * d;               // (n+1)*128 : xc0; amax overlays (xc0 dead)
    float* bufC = bufB + (size_t)(n + 1) * d;         // (n+1)*128 : xc1
    float* acc  = bufC + (size_t)(n + 1) * d;         // 1 float : attn loss sum
    int* amax = (int*)bufB;
    // attn partials overlay the head of bufC: consumed by reduce_kernel
    // before routing<false> writes bufC; row n untouched.
    float* partial = bufC;

    init_kernel<<<1, 256, 0, stream>>>(bufB, bufC, n);
    pca_gemm<<<(n + 31) / 32, 256, 0, stream>>>(x, pca_w, pca_b, bufA, n, nfeat);
    attn_prep<<<npart, 256, 0, stream>>>(bufA, ln_g, ln_b, w_qs, w_ks, bufB, partial, n);
    reduce_kernel<<<1, 256, 0, stream>>>(partial, acc, npart);
    routing_kernel<false><<<n, 64, 0, stream>>>(bufB, nb, bufC, nullptr, n);
    routing_kernel<true><<<n, 64, 0, stream>>>(bufC, nb, bufA, amax, n);
    meta_kernel<<<(n + 15) / 16, 256, 0, stream>>>(bufA, bufC, nb, amax, mlp_w, mlp_b, acc, out, n);
}